// Round 12
// baseline (197.152 us; speedup 1.0000x reference)
//
#include <hip/hip_runtime.h>
#include <hip/hip_bf16.h>
#include <math.h>

// Problem constants (from reference)
#define B_    2
#define N_    2048
#define D_    1024
#define DHAT_ 512
#define H_    16
#define F_    32      // qk head dim
#define G_    64      // v head dim
#define CHUNK 128
#define NCHUNK (N_ / CHUNK)   // 16
#define QKVLD 2048            // fused QKV row stride (Q 0..511 | K 512..1023 | V 1024..2047)

typedef __attribute__((ext_vector_type(8))) short bf16x8;
typedef __attribute__((ext_vector_type(4))) float f32x4;

__device__ __forceinline__ float phi_fn(float x) {
    return x > 0.0f ? x + 1.0f : expf(x);   // elu(x)+1
}

__device__ __forceinline__ ushort f2bf(float f) {
    unsigned u = __float_as_uint(f);
    u += 0x7FFFu + ((u >> 16) & 1u);
    return (ushort)(u >> 16);
}

__device__ __forceinline__ float bf2f(ushort u) {
    return __uint_as_float(((unsigned)u) << 16);
}

#define GLOAD_LDS16(g, l) __builtin_amdgcn_global_load_lds( \
    (const __attribute__((address_space(1))) void*)(g),     \
    (__attribute__((address_space(3))) void*)(l), 16, 0, 0)

// swizzle for 64B-row LDS tiles (rows of 32 bf16, 4 slots of 16B)
__device__ __forceinline__ int sw64(int row) { return (row & 3) ^ ((row >> 2) & 3); }
// swizzle for 256B-row tiles (rows of 128 bf16, 16 slots)
__device__ __forceinline__ int swP(int t) { return (t & 7) ^ (((t >> 3) & 1) << 1); }

// ---------------------------------------------------------------------------
// prep_kernel: ONE launch for  x->bf16 | 4 weight transposes | bias pack.
// ---------------------------------------------------------------------------
__device__ __forceinline__ void transpose_tile(
    const float* __restrict__ W, ushort* __restrict__ Wt,
    int K, int N, int bx, int by, int tid, ushort (*tile)[33])
{
    const int ti = by * 32, tj = bx * 32;
    const int tx = tid & 31, ty = tid >> 5;
    #pragma unroll
    for (int r = 0; r < 4; ++r)
        tile[ty + r * 8][tx] = f2bf(W[(size_t)(ti + ty + r * 8) * N + tj + tx]);
    __syncthreads();
    #pragma unroll
    for (int r = 0; r < 4; ++r)
        Wt[(size_t)(tj + ty + r * 8) * K + ti + tx] = tile[tx][ty + r * 8];
}

__global__ __launch_bounds__(256) void prep_kernel(
    const float* __restrict__ x,
    const float* __restrict__ wq, const float* __restrict__ wk,
    const float* __restrict__ wv, const float* __restrict__ wo,
    const float* __restrict__ bq, const float* __restrict__ bk,
    const float* __restrict__ bv,
    ushort* __restrict__ xbf, ushort* __restrict__ wqkvT,
    ushort* __restrict__ wot, float* __restrict__ bqkv)
{
    __shared__ ushort tile[32][33];
    const int id = blockIdx.x, tid = threadIdx.x;

    if (id < 4096) {
        int i = id * 256 + tid;
        float4 a = reinterpret_cast<const float4*>(x)[i];
        ushort4 o;
        o.x = f2bf(a.x); o.y = f2bf(a.y); o.z = f2bf(a.z); o.w = f2bf(a.w);
        reinterpret_cast<ushort4*>(xbf)[i] = o;
    } else if (id < 4608) {
        int tt = id - 4096;
        transpose_tile(wq, wqkvT, D_, DHAT_, tt & 15, tt >> 4, tid, tile);
    } else if (id < 5120) {
        int tt = id - 4608;
        transpose_tile(wk, wqkvT + (size_t)DHAT_ * D_, D_, DHAT_, tt & 15, tt >> 4, tid, tile);
    } else if (id < 6144) {
        int tt = id - 5120;
        transpose_tile(wv, wqkvT + (size_t)2 * DHAT_ * D_, D_, D_, tt & 31, tt >> 5, tid, tile);
    } else if (id < 7168) {
        int tt = id - 6144;
        transpose_tile(wo, wot, D_, D_, tt & 31, tt >> 5, tid, tile);
    } else {
        int i = (id - 7168) * 256 + tid;
        float v;
        if (i < DHAT_)          v = bq[i];
        else if (i < 2 * DHAT_) v = bk[i - DHAT_];
        else                    v = bv[i - 2 * DHAT_];
        bqkv[i] = v;
    }
}

// ---------------------------------------------------------------------------
// MFMA bf16 GEMM, BM=64, BK=64, single-buffer 2-barrier loop (round-10 version,
// unchanged). 4 waves (2x2): wave tile 32 x BN/2. + T1 XCD swizzle.
// ---------------------------------------------------------------------------
template<bool OUTBF, int BN>
__global__ __launch_bounds__(256) void mfma_gemm_kernel(
    const ushort* __restrict__ A, const ushort* __restrict__ Wt,
    const float* __restrict__ bias, void* __restrict__ Cout,
    int M, int K, int N, int phi_upto)
{
    constexpr int NF = BN / 32;               // n-frags per wave (128->4, 64->2)
    __shared__ __attribute__((aligned(16))) ushort Asm[64 * 64];    //  8 KB
    __shared__ __attribute__((aligned(16))) ushort Bsm[BN * 64];    // 16/8 KB

    const int tid  = threadIdx.x;
    const int lane = tid & 63;
    const int wave = tid >> 6;
    const int wr   = wave >> 1, wc = wave & 1;

    // T1: XCD-aware bijective remap (nwg % 8 == 0 for all our grids).
    const int nwg  = gridDim.x * gridDim.y;
    const int flat = blockIdx.y * gridDim.x + blockIdx.x;
    const int cpx  = nwg >> 3;
    const int swz  = (flat & 7) * cpx + (flat >> 3);
    const int bx   = swz % gridDim.x, by = swz / gridDim.x;

    const int brow = by * 64, bcol = bx * BN;
    const int l16  = lane & 15, lk = lane >> 4;

    f32x4 acc[2][NF];
    #pragma unroll
    for (int m = 0; m < 2; ++m)
        #pragma unroll
        for (int n = 0; n < NF; ++n)
            acc[m][n] = (f32x4){0.f, 0.f, 0.f, 0.f};

    for (int k0 = 0; k0 < K; k0 += 64) {
        __syncthreads();
        #pragma unroll
        for (int r = 0; r < 2; ++r) {         // A: 64 rows x 8 slots = 512
            int fi  = r * 256 + tid;
            int row = fi >> 3, sl = fi & 7;
            GLOAD_LDS16(&A[(size_t)(brow + row) * K + k0 + ((sl ^ (row & 7)) << 3)],
                        &Asm[fi * 8]);
        }
        #pragma unroll
        for (int r = 0; r < BN / 32; ++r) {   // B: BN rows x 8 slots
            int fi  = r * 256 + tid;
            int row = fi >> 3, sl = fi & 7;
            GLOAD_LDS16(&Wt[(size_t)(bcol + row) * K + k0 + ((sl ^ (row & 7)) << 3)],
                        &Bsm[fi * 8]);
        }
        __syncthreads();

        #pragma unroll
        for (int kk = 0; kk < 2; ++kk) {
            bf16x8 af[2], bf[NF];
            #pragma unroll
            for (int m = 0; m < 2; ++m) {
                int row = wr * 32 + m * 16 + l16;
                af[m] = *reinterpret_cast<const bf16x8*>(
                    &Asm[row * 64 + (((kk * 4 + lk) ^ (row & 7)) << 3)]);
            }
            #pragma unroll
            for (int n = 0; n < NF; ++n) {
                int row = wc * (BN / 2) + n * 16 + l16;
                bf[n] = *reinterpret_cast<const bf16x8*>(
                    &Bsm[row * 64 + (((kk * 4 + lk) ^ (row & 7)) << 3)]);
            }
            #pragma unroll
            for (int m = 0; m < 2; ++m)
                #pragma unroll
                for (int n = 0; n < NF; ++n)
                    acc[m][n] = __builtin_amdgcn_mfma_f32_16x16x32_bf16(af[m], bf[n], acc[m][n], 0, 0, 0);
        }
    }

    // C/D layout: col=lane&15, row=(lane>>4)*4+j  [m89/m91 verified]
    #pragma unroll
    for (int n = 0; n < NF; ++n) {
        int col = bcol + wc * (BN / 2) + n * 16 + l16;
        float bv = bias[col];
        const bool do_phi = col < phi_upto;
        #pragma unroll
        for (int m = 0; m < 2; ++m) {
            int row0 = brow + wr * 32 + m * 16 + lk * 4;
            #pragma unroll
            for (int j = 0; j < 4; ++j) {
                float v = acc[m][n][j] + bv;
                if (do_phi) v = phi_fn(v);
                if (OUTBF)
                    ((ushort*)Cout)[(size_t)(row0 + j) * N + col] = f2bf(v);
                else
                    ((float*)Cout)[(size_t)(row0 + j) * N + col] = v;
            }
        }
    }
}

// ---------------------------------------------------------------------------
// Pass A (MFMA): S_c[f][g] = sum_t K[t][f]*V[t][g],  z_c[f] = sum_t K[t][f]
// ---------------------------------------------------------------------------
__global__ __launch_bounds__(256) void chunk_kv_kernel(
    const ushort* __restrict__ QKV, float* __restrict__ Sb, float* __restrict__ zb)
{
    __shared__ __attribute__((aligned(16))) ushort KsT[32 * 128];   //  8 KB [f][t]
    __shared__ __attribute__((aligned(16))) ushort VsT[64 * 128];   // 16 KB [g][t]

    const int c = blockIdx.x, h = blockIdx.y, b = blockIdx.z;
    const int tid = threadIdx.x;
    const int lane = tid & 63, wave = tid >> 6;
    const int l16 = lane & 15, lk = lane >> 4;
    const size_t row0 = (size_t)b * N_ + (size_t)c * CHUNK;

    // stage K^T [f][t]
    #pragma unroll
    for (int r = 0; r < 2; ++r) {
        int fi = r * 256 + tid;
        int t = fi >> 2, f8 = (fi & 3) << 3;
        bf16x8 v = *reinterpret_cast<const bf16x8*>(&QKV[(row0 + t) * QKVLD + DHAT_ + h * F_ + f8]);
        #pragma unroll
        for (int i = 0; i < 8; ++i) {
            int f = f8 + i;
            KsT[f * 128 + (t ^ ((f & 7) << 3))] = (ushort)v[i];
        }
    }
    // stage V^T [g][t]
    {
        int s = tid & 127, gh = tid >> 7;
        const ushort* vsrc = &QKV[(row0 + s) * QKVLD + 2 * DHAT_ + h * G_ + gh * 32];
        #pragma unroll
        for (int w = 0; w < 4; ++w) {
            bf16x8 v = *reinterpret_cast<const bf16x8*>(&vsrc[w * 8]);
            #pragma unroll
            for (int i = 0; i < 8; ++i) {
                int g = gh * 32 + w * 8 + i;
                VsT[g * 128 + (s ^ ((g & 7) << 3))] = (ushort)v[i];
            }
        }
    }
    __syncthreads();

    // wave w owns g-tile w, f-tiles 0..1
    f32x4 sacc[2];
    sacc[0] = (f32x4){0.f, 0.f, 0.f, 0.f};
    sacc[1] = (f32x4){0.f, 0.f, 0.f, 0.f};
    const int g = wave * 16 + l16;
    #pragma unroll
    for (int ks = 0; ks < 4; ++ks) {
        int sl = ks * 4 + lk;
        bf16x8 bv = *reinterpret_cast<const bf16x8*>(&VsT[g * 128 + ((sl ^ (g & 7)) << 3)]);
        #pragma unroll
        for (int m = 0; m < 2; ++m) {
            int f = m * 16 + l16;
            bf16x8 ak = *reinterpret_cast<const bf16x8*>(&KsT[f * 128 + ((sl ^ (f & 7)) << 3)]);
            sacc[m] = __builtin_amdgcn_mfma_f32_16x16x32_bf16(ak, bv, sacc[m], 0, 0, 0);
        }
    }

    const size_t sbase = ((size_t)((b * H_ + h) * NCHUNK + c)) * (F_ * G_);
    #pragma unroll
    for (int m = 0; m < 2; ++m)
        #pragma unroll
        for (int j = 0; j < 4; ++j) {
            int f = m * 16 + lk * 4 + j;
            Sb[sbase + (size_t)f * G_ + g] = sacc[m][j];
        }

    // z[f]
    {
        int f = tid >> 3, i = tid & 7;
        float zs = 0.0f;
        #pragma unroll
        for (int ss = 0; ss < 2; ++ss) {
            int sl = i * 2 + ss;
            bf16x8 kv = *reinterpret_cast<const bf16x8*>(&KsT[f * 128 + ((sl ^ (f & 7)) << 3)]);
            #pragma unroll
            for (int e = 0; e < 8; ++e) zs += bf2f((ushort)kv[e]);
        }
        zs += __shfl_xor(zs, 1);
        zs += __shfl_xor(zs, 2);
        zs += __shfl_xor(zs, 4);
        if (i == 0) zb[((size_t)(b * H_ + h) * NCHUNK + c) * F_ + f] = zs;
    }
}

// ---------------------------------------------------------------------------
// Pass C (MFMA, scan fused): block sums its own S_prefix/z_prefix (L2-hot),
// then P = tril(QK^T); den = rowsum(P)+q.z_prefix; out = (P@V+Q@S)/den.
// ---------------------------------------------------------------------------
__global__ __launch_bounds__(256) void attn_mfma_kernel(
    const ushort* __restrict__ QKV, const float* __restrict__ Sb,
    const float* __restrict__ zb, ushort* __restrict__ Obf)
{
    __shared__ __attribute__((aligned(16))) ushort Qs[128 * 32];   //  8 KB [t][f]  sw64
    __shared__ __attribute__((aligned(16))) ushort Ks[128 * 32];   //  8 KB [s][f]  sw64
    __shared__ __attribute__((aligned(16))) ushort VsT[64 * 128];  // 16 KB [g][s]
    __shared__ __attribute__((aligned(16))) ushort Ss[64 * 32];    //  4 KB [g][f]  sw64
    __shared__ __attribute__((aligned(16))) ushort Ps[128 * 128];  // 32 KB [t][s]  swP
    __shared__ float zl[F_];
    __shared__ float denl[CHUNK];

    const int c = blockIdx.x, h = blockIdx.y, b = blockIdx.z;
    const int tid = threadIdx.x;
    const int lane = tid & 63, wave = tid >> 6;
    const int l16 = lane & 15, lk = lane >> 4;
    const size_t row0 = (size_t)b * N_ + (size_t)c * CHUNK;
    const int bh = b * H_ + h;

    // stage Q, K (source pre-swizzled -> linear LDS)
    #pragma unroll
    for (int r = 0; r < 2; ++r) {
        int fi = r * 256 + tid;
        int row = fi >> 2;
        int c8 = ((fi & 3) ^ sw64(row)) << 3;
        GLOAD_LDS16(&QKV[(row0 + row) * QKVLD + h * F_ + c8], &Qs[fi * 8]);
        GLOAD_LDS16(&QKV[(row0 + row) * QKVLD + DHAT_ + h * F_ + c8], &Ks[fi * 8]);
    }
    // S_prefix: sum fp32 chunk states cc < c, cvt bf16, write Ss [g][f] sw64
    {
        int g = tid >> 2, f0 = (tid & 3) << 3;
        float s[8] = {};
        for (int cc = 0; cc < c; ++cc) {
            const float* sp = &Sb[((size_t)bh * NCHUNK + cc) * (F_ * G_)];
            #pragma unroll
            for (int i = 0; i < 8; ++i) s[i] += sp[(size_t)(f0 + i) * G_ + g];
        }
        bf16x8 w;
        #pragma unroll
        for (int i = 0; i < 8; ++i) w[i] = (short)f2bf(s[i]);
        *reinterpret_cast<bf16x8*>(&Ss[g * 32 + ((((f0 >> 3)) ^ sw64(g)) << 3)]) = w;
    }
    // z_prefix
    if (tid < F_) {
        float pz = 0.0f;
        for (int cc = 0; cc < c; ++cc)
            pz += zb[((size_t)bh * NCHUNK + cc) * F_ + tid];
        zl[tid] = pz;
    }
    // stage V transposed [g][s]
    {
        int s = tid & 127, gh = tid >> 7;
        const ushort* vsrc = &QKV[(row0 + s) * QKVLD + 2 * DHAT_ + h * G_ + gh * 32];
        #pragma unroll
        for (int w = 0; w < 4; ++w) {
            bf16x8 v = *reinterpret_cast<const bf16x8*>(&vsrc[w * 8]);
            #pragma unroll
            for (int i = 0; i < 8; ++i) {
                int g = gh * 32 + w * 8 + i;
                VsT[g * 128 + (s ^ ((g & 7) << 3))] = (ushort)v[i];
            }
        }
    }
    __syncthreads();

    const int mbase = wave * 32;

    bf16x8 aq[2];
    #pragma unroll
    for (int m = 0; m < 2; ++m) {
        int row = mbase + m * 16 + l16;
        aq[m] = *reinterpret_cast<const bf16x8*>(&Qs[row * 32 + ((lk ^ sw64(row)) << 3)]);
    }

    // P = Q K^T (wave's 32 rows x 128 cols)
    f32x4 p[2][8];
    #pragma unroll
    for (int m = 0; m < 2; ++m)
        #pragma unroll
        for (int n = 0; n < 8; ++n)
            p[m][n] = (f32x4){0.f, 0.f, 0.f, 0.f};
    #pragma unroll
    for (int n = 0; n < 8; ++n) {
        int srow = n * 16 + l16;
        bf16x8 bk = *reinterpret_cast<const bf16x8*>(&Ks[srow * 32 + ((lk ^ sw64(srow)) << 3)]);
        p[0][n] = __builtin_amdgcn_mfma_f32_16x16x32_bf16(aq[0], bk, p[0][n], 0, 0, 0);
        p[1][n] = __builtin_amdgcn_mfma_f32_16x16x32_bf16(aq[1], bk, p[1][n], 0, 0, 0);
    }

    // causal mask + cvt + store Ps (swizzled)
    #pragma unroll
    for (int m = 0; m < 2; ++m)
        #pragma unroll
        for (int n = 0; n < 8; ++n) {
            int s = n * 16 + l16;
            #pragma unroll
            for (int j = 0; j < 4; ++j) {
                int t = mbase + m * 16 + lk * 4 + j;
                float v = (s <= t) ? p[m][n][j] : 0.0f;
                Ps[t * 128 + ((s & 7) | (((s >> 3) ^ swP(t)) << 3))] = f2bf(v);
            }
        }

    // den[t]
    {
        int t = tid >> 1, h2 = tid & 1;
        float rs = 0.0f;
        #pragma unroll
        for (int r = 0; r < 8; ++r) {
            int sl = h2 * 8 + r;
            bf16x8 pv = *reinterpret_cast<const bf16x8*>(&Ps[t * 128 + ((sl ^ swP(t)) << 3)]);
            #pragma unroll
            for (int i = 0; i < 8; ++i) rs += bf2f((ushort)pv[i]);
        }
        #pragma unroll
        for (int ss = 0; ss < 2; ++ss) {
            int sl = h2 * 2 + ss;
            bf16x8 qv = *reinterpret_cast<const bf16x8*>(&Qs[t * 32 + ((sl ^ sw64(t)) << 3)]);
            #pragma unroll
            for (int i = 0; i < 8; ++i) rs += bf2f((ushort)qv[i]) * zl[sl * 8 + i];
        }
        rs += __shfl_xor(rs, 1);
        if (h2 == 0) denl[t] = rs + 1e-6f;
    }

    // out = Q @ S_prefix + P @ V
    f32x4 o[2][4];
    #pragma unroll
    for (int m = 0; m < 2; ++m)
        #pragma unroll
        for (int n = 0; n < 4; ++n)
            o[m][n] = (f32x4){0.f, 0.f, 0.f, 0.f};
    #pragma unroll
    for (int n = 0; n < 4; ++n) {
        int g = n * 16 + l16;
        bf16x8 bs = *reinterpret_cast<const bf16x8*>(&Ss[g * 32 + ((lk ^ sw64(g)) << 3)]);
        o[0][n] = __builtin_amdgcn_mfma_f32_16x16x32_bf16(aq[0], bs, o[0][n], 0, 0, 0);
        o[1][n] = __builtin_amdgcn_mfma_f32_16x16x32_bf16(aq[1], bs, o[1][n], 0, 0, 0);
    }
    #pragma unroll
    for (int ks = 0; ks < 4; ++ks) {
        bf16x8 ap[2];
        #pragma unroll
        for (int m = 0; m < 2; ++m) {
            int t = mbase + m * 16 + l16;
            int sl = ks * 4 + lk;
            ap[m] = *reinterpret_cast<const bf16x8*>(&Ps[t * 128 + ((sl ^ swP(t)) << 3)]);
        }
        #pragma unroll
        for (int n = 0; n < 4; ++n) {
            int g = n * 16 + l16;
            bf16x8 bv = *reinterpret_cast<const bf16x8*>(&VsT[g * 128 + (((ks * 4 + lk) ^ (g & 7)) << 3)]);
            o[0][n] = __builtin_amdgcn_mfma_f32_16x16x32_bf16(ap[0], bv, o[0][n], 0, 0, 0);
            o[1][n] = __builtin_amdgcn_mfma_f32_16x16x32_bf16(ap[1], bv, o[1][n], 0, 0, 0);
        }
    }

    // epilogue
    #pragma unroll
    for (int m = 0; m < 2; ++m)
        #pragma unroll
        for (int j = 0; j < 4; ++j) {
            int t = mbase + m * 16 + lk * 4 + j;
            float rinv = 1.0f / denl[t];
            #pragma unroll
            for (int n = 0; n < 4; ++n) {
                int g = n * 16 + l16;
                Obf[(row0 + t) * D_ + h * G_ + g] = f2bf(o[m][n][j] * rinv);
            }
        }
}

// ---------------------------------------------------------------------------
extern "C" void kernel_launch(void* const* d_in, const int* in_sizes, int n_in,
                              void* d_out, int out_size, void* d_ws, size_t ws_size,
                              hipStream_t stream) {
    const float* x  = (const float*)d_in[0];
    const float* wq = (const float*)d_in[1];
    const float* bq = (const float*)d_in[2];
    const float* wk = (const float*)d_in[3];
    const float* bk = (const float*)d_in[4];
    const float* wv = (const float*)d_in[5];
    const float* bv = (const float*)d_in[6];
    const float* wo = (const float*)d_in[7];
    const float* bo = (const float*)d_in[8];
    float* out = (float*)d_out;

    size_t off = 0;
    char* base = (char*)d_ws;
    auto alloc = [&](size_t bytes) -> void* {
        void* p = base + off;
        off += (bytes + 255) & ~(size_t)255;
        return p;
    };
    const size_t MN = (size_t)B_ * N_;   // 4096
    ushort* QKV   = (ushort*)alloc(MN * QKVLD * 2);
    float*  Sb    = (float*) alloc((size_t)B_ * H_ * NCHUNK * F_ * G_ * 4);
    float*  zb    = (float*) alloc((size_t)B_ * H_ * NCHUNK * F_ * 4);
    ushort* xbf   = (ushort*)alloc(MN * D_ * 2);
    ushort* wqkvT = (ushort*)alloc((size_t)QKVLD * D_ * 2);
    ushort* wot   = (ushort*)alloc((size_t)D_ * D_ * 2);
    float*  bqkv  = (float*) alloc((size_t)QKVLD * 4);
    ushort* obf   = (ushort*)alloc(MN * D_ * 2);
    // measurement scratch (round 11: idempotent duplicate GEMM launches)
    ushort* QKV2  = (ushort*)alloc(MN * QKVLD * 2);
    float*  out2  = (float*) alloc(MN * D_ * 4);

    const int M = (int)MN;   // 4096

    // one prep launch: convert + 4 transposes + bias pack
    prep_kernel<<<dim3(7176), 256, 0, stream>>>(
        x, wq, wk, wv, wo, bq, bk, bv, xbf, wqkvT, wot, bqkv);

    // fused QKV projection: BM=64 -> grid (16,64) = 1024 WGs = 4 blocks/CU
    mfma_gemm_kernel<true, 128><<<dim3(QKVLD / 128, M / 64), 256, 0, stream>>>(
        xbf, wqkvT, bqkv, QKV, M, D_, QKVLD, 2 * DHAT_);
    // MEASUREMENT: duplicate QKV GEMM into scratch (dur delta isolates its cost)
    mfma_gemm_kernel<true, 128><<<dim3(QKVLD / 128, M / 64), 256, 0, stream>>>(
        xbf, wqkvT, bqkv, QKV2, M, D_, QKVLD, 2 * DHAT_);

    // chunked linear attention (scan fused into attn)
    chunk_kv_kernel<<<dim3(NCHUNK, H_, B_), 256, 0, stream>>>(QKV, Sb, zb);
    attn_mfma_kernel<<<dim3(NCHUNK, H_, B_), 256, 0, stream>>>(QKV, Sb, zb, obf);

    // output projection: BM=64/BN=64 -> grid (16,64) = 1024 WGs = 4 blocks/CU
    mfma_gemm_kernel<false, 64><<<dim3(D_ / 64, M / 64), 256, 0, stream>>>(
        obf, wot, bo, out, M, D_, D_, 0);
    // MEASUREMENT: duplicate wo GEMM into scratch
    mfma_gemm_kernel<false, 64><<<dim3(D_ / 64, M / 64), 256, 0, stream>>>(
        obf, wot, bo, out2, M, D_, D_, 0);
}